// Round 4
// baseline (668.046 us; speedup 1.0000x reference)
//
#include <hip/hip_runtime.h>
#include <hip/hip_bf16.h>

#define NNODES 50000
#define NEDGES 800000
#define NDIM   128
#define EDIM   64
#define K1     192   // NDIM + EDIM
#define K2     256   // 2*NDIM
#define NB     196   // ceil(NNODES/256) scan blocks

#define KPA 136      // LDS k-stride for K=128
#define KPU 264      // LDS k-stride for K=256

typedef __attribute__((ext_vector_type(8))) short bf16x8;
typedef __attribute__((ext_vector_type(4))) short bf16x4;
typedef __attribute__((ext_vector_type(4))) float f32x4;

__device__ inline short f2bf(float f) {
  union { float f; unsigned u; } v; v.f = f;
  unsigned r = v.u + 0x7FFFu + ((v.u >> 16) & 1u);   // round-to-nearest-even
  return (short)(r >> 16);
}

__device__ inline bf16x4 pack4(float4 v) {
  bf16x4 p;
  p[0] = f2bf(v.x); p[1] = f2bf(v.y); p[2] = f2bf(v.z); p[3] = f2bf(v.w);
  return p;
}

// fp32 -> bf16 streaming convert (float4 per thread)
__global__ __launch_bounds__(256) void cvt_kernel(const float* __restrict__ src,
                                                  short* __restrict__ dst, int n) {
  int i = (blockIdx.x * 256 + threadIdx.x) * 4;
  if (i < n) {
    float4 v = *(const float4*)(src + i);
    *(bf16x4*)(dst + i) = pack4(v);
  }
}

// Transpose+convert all 4 fp32 weights [K][128] -> bf16 [n][K] in one launch
__global__ __launch_bounds__(256) void wt_all_kernel(const float* __restrict__ w1,
                                                     const float* __restrict__ w2,
                                                     const float* __restrict__ u1,
                                                     const float* __restrict__ u2,
                                                     short* __restrict__ w1t,
                                                     short* __restrict__ w2t,
                                                     short* __restrict__ u1t,
                                                     short* __restrict__ u2t) {
  int i = blockIdx.x * 256 + threadIdx.x;
  const int A0 = K1 * 128;          // 24576
  const int A1 = A0 + 128 * 128;    // 40960
  const int A2 = A1 + K2 * 128;    // 73728
  const int A3 = A2 + 128 * 128;   // 90112
  if (i < A0) {
    int j = i, k = j >> 7, n = j & 127;
    w1t[n * K1 + k] = f2bf(w1[j]);
  } else if (i < A1) {
    int j = i - A0, k = j >> 7, n = j & 127;
    w2t[n * NDIM + k] = f2bf(w2[j]);
  } else if (i < A2) {
    int j = i - A1, k = j >> 7, n = j & 127;
    u1t[n * K2 + k] = f2bf(u1[j]);
  } else if (i < A3) {
    int j = i - A2, k = j >> 7, n = j & 127;
    u2t[n * NDIM + k] = f2bf(u2[j]);
  }
}

// ---- counting-sort pipeline: sort edges by src ----
__global__ __launch_bounds__(256) void hist_kernel(const int* __restrict__ eidx,
                                                   int* __restrict__ cnt) {
  int i = blockIdx.x * 256 + threadIdx.x;
  if (i < NEDGES) atomicAdd(&cnt[eidx[i]], 1);
}

__global__ __launch_bounds__(256) void scan_reduce_kernel(const int* __restrict__ cnt,
                                                          int* __restrict__ bsum) {
  __shared__ int sh[256];
  int tid = threadIdx.x;
  int i = blockIdx.x * 256 + tid;
  sh[tid] = (i < NNODES) ? cnt[i] : 0;
  __syncthreads();
#pragma unroll
  for (int off = 128; off > 0; off >>= 1) {
    if (tid < off) sh[tid] += sh[tid + off];
    __syncthreads();
  }
  if (tid == 0) bsum[blockIdx.x] = sh[0];
}

__global__ __launch_bounds__(256) void scan_top_kernel(const int* __restrict__ bsum,
                                                       int* __restrict__ bscan) {
  __shared__ int sh[256];
  int tid = threadIdx.x;
  int v = (tid < NB) ? bsum[tid] : 0;
  sh[tid] = v;
  __syncthreads();
#pragma unroll
  for (int off = 1; off < 256; off <<= 1) {
    int t = (tid >= off) ? sh[tid - off] : 0;
    __syncthreads();
    sh[tid] += t;
    __syncthreads();
  }
  bscan[tid] = sh[tid] - v;   // exclusive
}

__global__ __launch_bounds__(256) void scan_down_kernel(int* __restrict__ cnt,
                                                        const int* __restrict__ bscan,
                                                        int* __restrict__ row_ptr) {
  __shared__ int sh[256];
  int tid = threadIdx.x;
  int i = blockIdx.x * 256 + tid;
  int v = (i < NNODES) ? cnt[i] : 0;
  sh[tid] = v;
  __syncthreads();
#pragma unroll
  for (int off = 1; off < 256; off <<= 1) {
    int t = (tid >= off) ? sh[tid - off] : 0;
    __syncthreads();
    sh[tid] += t;
    __syncthreads();
  }
  if (i < NNODES) {
    row_ptr[i] = bscan[blockIdx.x] + (sh[tid] - v);
    cnt[i] = 0;                 // reset: becomes ticket counter, ends as degree
  }
}

__global__ __launch_bounds__(256) void permute_kernel(const int* __restrict__ eidx,
                                                      const int* __restrict__ row_ptr,
                                                      int* __restrict__ cnt,
                                                      int4* __restrict__ s_edges) {
  int e = blockIdx.x * 256 + threadIdx.x;
  if (e < NEDGES) {
    int s = eidx[e];
    int d = eidx[NEDGES + e];
    int pos = row_ptr[s] + atomicAdd(&cnt[s], 1);
    s_edges[pos] = make_int4(s, d, e, 0);
  }
}

// ---- edge kernel (row-owned waves, single barrier):
//      wave w owns edges e0+w*16 .. +16 across ALL 128 cols (nt=0..7).
//      A fragments load straight from global (no X staging, no X conflicts).
//      W1 staged once in LDS with 16B-slot XOR swizzle (slot ^= n&7).
//      Epilogue: per-lane 4-contiguous-row register run-aggregation, atomics
//      issued with quad-uniform branches (16-lane 64B bursts), never drained
//      by a barrier. LDS 48KB -> 3 blocks/CU. ----
__global__ __launch_bounds__(256, 3) void edge_kernel(const short* __restrict__ nf_bf,
                                                      const float* __restrict__ edge_feats,
                                                      const int4* __restrict__ s_edges,
                                                      const short* __restrict__ w1t,
                                                      const float* __restrict__ b1,
                                                      float* __restrict__ hagg) {
  __shared__ __align__(16) short B[128 * K1];   // 49152 B, swizzled 16B slots

  const int tid = threadIdx.x;
  const int e0 = blockIdx.x * 64;
  const int lane = tid & 63;
  const int wv = tid >> 6;
  const int m16 = lane & 15;
  const int quad = lane >> 4;

  // ---- own-edge record + A-fragment loads (independent of LDS) ----
  const int row = (wv << 4) + m16;
  const int4 rec = s_edges[e0 + row];        // {src, dst, eid, 0}; 4 quads share line
  bf16x8 a[6];
  {
    const short* np = nf_bf + (size_t)rec.y * NDIM + quad * 8;
#pragma unroll
    for (int ks = 0; ks < 4; ++ks) a[ks] = *(const bf16x8*)(np + ks * 32);
    const float* ep = edge_feats + (size_t)rec.z * EDIM + quad * 8;
#pragma unroll
    for (int ks = 0; ks < 2; ++ks) {
      float4 lo = *(const float4*)(ep + ks * 32);
      float4 hi = *(const float4*)(ep + ks * 32 + 4);
      bf16x4 pl = pack4(lo), ph = pack4(hi);
      bf16x8 p;
      p[0] = pl[0]; p[1] = pl[1]; p[2] = pl[2]; p[3] = pl[3];
      p[4] = ph[0]; p[5] = ph[1]; p[6] = ph[2]; p[7] = ph[3];
      a[4 + ks] = p;
    }
  }
  // srcs of my 4 output rows (wv*16 + quad*4 .. +3) and bias for my 8 cols
  const int* sp = (const int*)(s_edges + e0 + (wv << 4) + (quad << 2));
  const int sa = sp[0], sb = sp[4], sc = sp[8], sd = sp[12];
  float bias[8];
#pragma unroll
  for (int nt = 0; nt < 8; ++nt) bias[nt] = b1[nt * 16 + m16];

  // ---- stage W1 -> LDS: row n, 24 slots of 16B, slot ^= (n&7) ----
  {
    const int n = tid >> 1;
    const int h = tid & 1;
    const short* src = w1t + n * K1 + h * 96;
    short* drow = B + n * K1;
    const int x7 = n & 7;
#pragma unroll
    for (int j = 0; j < 12; ++j) {
      const int s = h * 12 + j;
      *(bf16x8*)(drow + ((s ^ x7) << 3)) = *(const bf16x8*)(src + j * 8);
    }
  }
  __syncthreads();   // the only barrier

  // ---- MFMA: 8 col-tiles x 6 k-steps ----
  f32x4 acc[8];
#pragma unroll
  for (int nt = 0; nt < 8; ++nt) acc[nt] = (f32x4){0.f, 0.f, 0.f, 0.f};
  const int x7 = m16 & 7;
#pragma unroll
  for (int ks = 0; ks < 6; ++ks) {
    const int so = ((ks * 4 + quad) ^ x7) << 3;
#pragma unroll
    for (int nt = 0; nt < 8; ++nt) {
      bf16x8 b = *(const bf16x8*)(B + (nt * 16 + m16) * K1 + so);
      acc[nt] = __builtin_amdgcn_mfma_f32_16x16x32_bf16(a[ks], b, acc[nt], 0, 0, 0);
    }
  }

  // ---- epilogue: bias+lrelu, 4-row register run-aggregation, atomics ----
  const bool k1 = (sb != sa), k2 = (sc != sb), k3 = (sd != sc);
#pragma unroll
  for (int nt = 0; nt < 8; ++nt) {
    const float bb = bias[nt];
    float v0 = acc[nt][0] + bb; v0 = v0 >= 0.f ? v0 : 0.2f * v0;
    float v1 = acc[nt][1] + bb; v1 = v1 >= 0.f ? v1 : 0.2f * v1;
    float v2 = acc[nt][2] + bb; v2 = v2 >= 0.f ? v2 : 0.2f * v2;
    float v3 = acc[nt][3] + bb; v3 = v3 >= 0.f ? v3 : 0.2f * v3;
    const int c = nt * 16 + m16;
    float run = v0; int prev = sa;
    if (k1) { atomicAdd(&hagg[(size_t)prev * NDIM + c], run); run = v1; prev = sb; }
    else    { run += v1; }
    if (k2) { atomicAdd(&hagg[(size_t)prev * NDIM + c], run); run = v2; prev = sc; }
    else    { run += v2; }
    if (k3) { atomicAdd(&hagg[(size_t)prev * NDIM + c], run); run = v3; prev = sd; }
    else    { run += v3; }
    atomicAdd(&hagg[(size_t)prev * NDIM + c], run);
  }
}

// ---- node kernel: agg = hagg@W2 + deg*b2; out = lrelu(concat(x,agg)@U1+ub1)@U2+ub2
//      32-row tiles: LDS 25.7KB -> 6 blocks/CU ----
__global__ __launch_bounds__(256) void node_kernel(const short* __restrict__ nf_bf,
                                                   const float* __restrict__ hagg,
                                                   const int* __restrict__ degc,
                                                   const short* __restrict__ w2t,
                                                   const float* __restrict__ b2,
                                                   const short* __restrict__ u1t,
                                                   const float* __restrict__ ub1,
                                                   const short* __restrict__ u2t,
                                                   const float* __restrict__ ub2,
                                                   float* __restrict__ out) {
  __shared__ __align__(16) short AGH[32 * KPA];   // phase1: hagg tile; phase3: h2 tile
  __shared__ __align__(16) short XU[32 * KPU];    // concat(x, agg) tile
  __shared__ float degs[32];

  const int tid = threadIdx.x;
  const int n0 = blockIdx.x * 32;

  if (tid < 32) {
    int node = n0 + tid;
    degs[tid] = (node < NNODES) ? (float)degc[node] : 0.f;
  }
  {
    int r = tid >> 3, q = tid & 7;
    int node = n0 + r; if (node >= NNODES) node = NNODES - 1;
    const float4* hp = (const float4*)(hagg + (size_t)node * NDIM) + q * 4;
    const bf16x8* xp = (const bf16x8*)(nf_bf + (size_t)node * NDIM) + q * 2;
    short* ap = AGH + r * KPA + q * 16;
    short* xq = XU + r * KPU + q * 16;
#pragma unroll
    for (int j = 0; j < 4; ++j) *(bf16x4*)(ap + j * 4) = pack4(hp[j]);
#pragma unroll
    for (int j = 0; j < 2; ++j) *(bf16x8*)(xq + j * 8) = xp[j];
  }
  __syncthreads();

  const int lane = tid & 63;
  const int wv = tid >> 6;
  const int m16 = lane & 15;
  const int quad = lane >> 4;

  f32x4 acc[2][2];

  // ---- GEMM-a: agg = AGH @ W2 (K=128) ----
#pragma unroll
  for (int mt = 0; mt < 2; ++mt)
#pragma unroll
    for (int nt = 0; nt < 2; ++nt)
      acc[mt][nt] = (f32x4){0.f, 0.f, 0.f, 0.f};
#pragma unroll
  for (int ks = 0; ks < 4; ++ks) {
    const int k0 = ks * 32 + quad * 8;
    bf16x8 b[2];
#pragma unroll
    for (int nt = 0; nt < 2; ++nt) {
      int n = wv * 32 + nt * 16 + m16;
      b[nt] = *(const bf16x8*)(w2t + n * NDIM + k0);
    }
#pragma unroll
    for (int mt = 0; mt < 2; ++mt) {
      bf16x8 a = *(const bf16x8*)(AGH + (mt * 16 + m16) * KPA + k0);
#pragma unroll
      for (int nt = 0; nt < 2; ++nt)
        acc[mt][nt] = __builtin_amdgcn_mfma_f32_16x16x32_bf16(a, b[nt], acc[mt][nt], 0, 0, 0);
    }
  }
#pragma unroll
  for (int nt = 0; nt < 2; ++nt) {
    int col = wv * 32 + nt * 16 + m16;
    float bb = b2[col];
#pragma unroll
    for (int mt = 0; mt < 2; ++mt) {
#pragma unroll
      for (int i = 0; i < 4; ++i) {
        int row = mt * 16 + quad * 4 + i;
        float v = acc[mt][nt][i] + degs[row] * bb;
        XU[row * KPU + NDIM + col] = f2bf(v);
      }
    }
  }
  __syncthreads();

  // ---- GEMM-b: t = XU @ U1 (K=256), lrelu -> AGH ----
#pragma unroll
  for (int mt = 0; mt < 2; ++mt)
#pragma unroll
    for (int nt = 0; nt < 2; ++nt)
      acc[mt][nt] = (f32x4){0.f, 0.f, 0.f, 0.f};
#pragma unroll
  for (int ks = 0; ks < 8; ++ks) {
    const int k0 = ks * 32 + quad * 8;
    bf16x8 b[2];
#pragma unroll
    for (int nt = 0; nt < 2; ++nt) {
      int n = wv * 32 + nt * 16 + m16;
      b[nt] = *(const bf16x8*)(u1t + n * K2 + k0);
    }
#pragma unroll
    for (int mt = 0; mt < 2; ++mt) {
      bf16x8 a = *(const bf16x8*)(XU + (mt * 16 + m16) * KPU + k0);
#pragma unroll
      for (int nt = 0; nt < 2; ++nt)
        acc[mt][nt] = __builtin_amdgcn_mfma_f32_16x16x32_bf16(a, b[nt], acc[mt][nt], 0, 0, 0);
    }
  }
  __syncthreads();
#pragma unroll
  for (int nt = 0; nt < 2; ++nt) {
    int col = wv * 32 + nt * 16 + m16;
    float bb = ub1[col];
#pragma unroll
    for (int mt = 0; mt < 2; ++mt) {
#pragma unroll
      for (int i = 0; i < 4; ++i) {
        int row = mt * 16 + quad * 4 + i;
        float v = acc[mt][nt][i] + bb;
        v = v >= 0.f ? v : 0.2f * v;
        AGH[row * KPA + col] = f2bf(v);
      }
    }
  }
  __syncthreads();

  // ---- GEMM-c: out = h2 @ U2 (K=128) + ub2 ----
#pragma unroll
  for (int mt = 0; mt < 2; ++mt)
#pragma unroll
    for (int nt = 0; nt < 2; ++nt)
      acc[mt][nt] = (f32x4){0.f, 0.f, 0.f, 0.f};
#pragma unroll
  for (int ks = 0; ks < 4; ++ks) {
    const int k0 = ks * 32 + quad * 8;
    bf16x8 b[2];
#pragma unroll
    for (int nt = 0; nt < 2; ++nt) {
      int n = wv * 32 + nt * 16 + m16;
      b[nt] = *(const bf16x8*)(u2t + n * NDIM + k0);
    }
#pragma unroll
    for (int mt = 0; mt < 2; ++mt) {
      bf16x8 a = *(const bf16x8*)(AGH + (mt * 16 + m16) * KPA + k0);
#pragma unroll
      for (int nt = 0; nt < 2; ++nt)
        acc[mt][nt] = __builtin_amdgcn_mfma_f32_16x16x32_bf16(a, b[nt], acc[mt][nt], 0, 0, 0);
    }
  }
#pragma unroll
  for (int nt = 0; nt < 2; ++nt) {
    int col = wv * 32 + nt * 16 + m16;
    float bb = ub2[col];
#pragma unroll
    for (int mt = 0; mt < 2; ++mt) {
#pragma unroll
      for (int i = 0; i < 4; ++i) {
        int row = mt * 16 + quad * 4 + i;
        int node = n0 + row;
        if (node < NNODES)
          out[(size_t)node * NDIM + col] = acc[mt][nt][i] + bb;
      }
    }
  }
}

extern "C" void kernel_launch(void* const* d_in, const int* in_sizes, int n_in,
                              void* d_out, int out_size, void* d_ws, size_t ws_size,
                              hipStream_t stream) {
  const float* node_feats = (const float*)d_in[0];
  const float* edge_feats = (const float*)d_in[1];
  const float* msg_w1 = (const float*)d_in[2];
  const float* msg_b1 = (const float*)d_in[3];
  const float* msg_w2 = (const float*)d_in[4];
  const float* msg_b2 = (const float*)d_in[5];
  const float* upd_w1 = (const float*)d_in[6];
  const float* upd_b1 = (const float*)d_in[7];
  const float* upd_w2 = (const float*)d_in[8];
  const float* upd_b2 = (const float*)d_in[9];
  const int* eidx = (const int*)d_in[10];

  // ws layout (16B-aligned sections)
  float* hagg   = (float*)d_ws;                        // N*128 f32
  int* cnt      = (int*)(hagg + (size_t)NNODES * NDIM);// N (zeroed with hagg)
  int* row_ptr  = cnt + NNODES;                        // N
  int* bsum     = row_ptr + NNODES;                    // 256
  int* bscan    = bsum + 256;                          // 256
  int4* s_edges = (int4*)(bscan + 256);                // E int4
  short* w1t    = (short*)(s_edges + NEDGES);          // 128*K1 bf16
  short* w2t    = w1t + 128 * K1;
  short* u1t    = w2t + 128 * 128;
  short* u2t    = u1t + 128 * K2;
  short* nf_bf  = u2t + 128 * 128;                     // N*128 bf16

  hipMemsetAsync(d_ws, 0, (size_t)(NNODES * NDIM + NNODES) * sizeof(float), stream);

  cvt_kernel<<<(NNODES * NDIM / 4 + 255) / 256, 256, 0, stream>>>(node_feats, nf_bf,
                                                                  NNODES * NDIM);
  wt_all_kernel<<<(90112 + 255) / 256, 256, 0, stream>>>(msg_w1, msg_w2, upd_w1, upd_w2,
                                                         w1t, w2t, u1t, u2t);

  hist_kernel<<<NEDGES / 256, 256, 0, stream>>>(eidx, cnt);
  scan_reduce_kernel<<<NB, 256, 0, stream>>>(cnt, bsum);
  scan_top_kernel<<<1, 256, 0, stream>>>(bsum, bscan);
  scan_down_kernel<<<NB, 256, 0, stream>>>(cnt, bscan, row_ptr);
  permute_kernel<<<NEDGES / 256, 256, 0, stream>>>(eidx, row_ptr, cnt, s_edges);

  edge_kernel<<<NEDGES / 64, 256, 0, stream>>>(nf_bf, edge_feats, s_edges,
                                               w1t, msg_b1, hagg);
  node_kernel<<<(NNODES + 31) / 32, 256, 0, stream>>>(nf_bf, hagg, cnt,
                                                      w2t, msg_b2, u1t, upd_b1,
                                                      u2t, upd_b2, (float*)d_out);
}

// Round 5
// 507.334 us; speedup vs baseline: 1.3168x; 1.3168x over previous
//
#include <hip/hip_runtime.h>
#include <hip/hip_bf16.h>

#define NNODES 50000
#define NEDGES 800000
#define NDIM   128
#define EDIM   64
#define K1     192   // NDIM + EDIM
#define K2     256   // 2*NDIM
#define NB     196   // ceil(NNODES/256) scan blocks
#define TPB_E  4     // edge tiles (64 edges) per block

#define KPA 136      // LDS k-stride for K=128
#define KPU 264      // LDS k-stride for K=256

typedef __attribute__((ext_vector_type(8))) short bf16x8;
typedef __attribute__((ext_vector_type(4))) short bf16x4;
typedef __attribute__((ext_vector_type(4))) float f32x4;

__device__ inline short f2bf(float f) {
  union { float f; unsigned u; } v; v.f = f;
  unsigned r = v.u + 0x7FFFu + ((v.u >> 16) & 1u);   // round-to-nearest-even
  return (short)(r >> 16);
}

__device__ inline bf16x4 pack4(float4 v) {
  bf16x4 p;
  p[0] = f2bf(v.x); p[1] = f2bf(v.y); p[2] = f2bf(v.z); p[3] = f2bf(v.w);
  return p;
}

// LDS-only barrier: does NOT drain vmcnt (atomics / prefetch stay in flight)
__device__ inline void wg_barrier_lds() {
  asm volatile("s_waitcnt lgkmcnt(0)" ::: "memory");
  __builtin_amdgcn_s_barrier();
  asm volatile("" ::: "memory");
}

// fp32 -> bf16 streaming convert (float4 per thread)
__global__ __launch_bounds__(256) void cvt_kernel(const float* __restrict__ src,
                                                  short* __restrict__ dst, int n) {
  int i = (blockIdx.x * 256 + threadIdx.x) * 4;
  if (i < n) {
    float4 v = *(const float4*)(src + i);
    *(bf16x4*)(dst + i) = pack4(v);
  }
}

// Transpose+convert all 4 fp32 weights [K][128] -> bf16 [n][K] in one launch
__global__ __launch_bounds__(256) void wt_all_kernel(const float* __restrict__ w1,
                                                     const float* __restrict__ w2,
                                                     const float* __restrict__ u1,
                                                     const float* __restrict__ u2,
                                                     short* __restrict__ w1t,
                                                     short* __restrict__ w2t,
                                                     short* __restrict__ u1t,
                                                     short* __restrict__ u2t) {
  int i = blockIdx.x * 256 + threadIdx.x;
  const int A0 = K1 * 128;          // 24576
  const int A1 = A0 + 128 * 128;    // 40960
  const int A2 = A1 + K2 * 128;     // 73728
  const int A3 = A2 + 128 * 128;    // 90112
  if (i < A0) {
    int j = i, k = j >> 7, n = j & 127;
    w1t[n * K1 + k] = f2bf(w1[j]);
  } else if (i < A1) {
    int j = i - A0, k = j >> 7, n = j & 127;
    w2t[n * NDIM + k] = f2bf(w2[j]);
  } else if (i < A2) {
    int j = i - A1, k = j >> 7, n = j & 127;
    u1t[n * K2 + k] = f2bf(u1[j]);
  } else if (i < A3) {
    int j = i - A2, k = j >> 7, n = j & 127;
    u2t[n * NDIM + k] = f2bf(u2[j]);
  }
}

// ---- counting-sort pipeline: sort edges by src ----
__global__ __launch_bounds__(256) void hist_kernel(const int* __restrict__ eidx,
                                                   int* __restrict__ cnt) {
  int i = blockIdx.x * 256 + threadIdx.x;
  if (i < NEDGES) atomicAdd(&cnt[eidx[i]], 1);
}

__global__ __launch_bounds__(256) void scan_reduce_kernel(const int* __restrict__ cnt,
                                                          int* __restrict__ bsum) {
  __shared__ int sh[256];
  int tid = threadIdx.x;
  int i = blockIdx.x * 256 + tid;
  sh[tid] = (i < NNODES) ? cnt[i] : 0;
  __syncthreads();
#pragma unroll
  for (int off = 128; off > 0; off >>= 1) {
    if (tid < off) sh[tid] += sh[tid + off];
    __syncthreads();
  }
  if (tid == 0) bsum[blockIdx.x] = sh[0];
}

__global__ __launch_bounds__(256) void scan_top_kernel(const int* __restrict__ bsum,
                                                       int* __restrict__ bscan) {
  __shared__ int sh[256];
  int tid = threadIdx.x;
  int v = (tid < NB) ? bsum[tid] : 0;
  sh[tid] = v;
  __syncthreads();
#pragma unroll
  for (int off = 1; off < 256; off <<= 1) {
    int t = (tid >= off) ? sh[tid - off] : 0;
    __syncthreads();
    sh[tid] += t;
    __syncthreads();
  }
  bscan[tid] = sh[tid] - v;   // exclusive
}

__global__ __launch_bounds__(256) void scan_down_kernel(int* __restrict__ cnt,
                                                        const int* __restrict__ bscan,
                                                        int* __restrict__ row_ptr) {
  __shared__ int sh[256];
  int tid = threadIdx.x;
  int i = blockIdx.x * 256 + tid;
  int v = (i < NNODES) ? cnt[i] : 0;
  sh[tid] = v;
  __syncthreads();
#pragma unroll
  for (int off = 1; off < 256; off <<= 1) {
    int t = (tid >= off) ? sh[tid - off] : 0;
    __syncthreads();
    sh[tid] += t;
    __syncthreads();
  }
  if (i < NNODES) {
    row_ptr[i] = bscan[blockIdx.x] + (sh[tid] - v);
    cnt[i] = 0;                 // reset: becomes ticket counter, ends as degree
  }
}

__global__ __launch_bounds__(256) void permute_kernel(const int* __restrict__ eidx,
                                                      const int* __restrict__ row_ptr,
                                                      int* __restrict__ cnt,
                                                      int4* __restrict__ s_edges) {
  int e = blockIdx.x * 256 + threadIdx.x;
  if (e < NEDGES) {
    int s = eidx[e];
    int d = eidx[NEDGES + e];
    int pos = row_ptr[s] + atomicAdd(&cnt[s], 1);
    s_edges[pos] = make_int4(s, d, e, 0);
  }
}

// ---- edge kernel v5: R2 tile/epilogue structure + 4-tile software pipeline.
//      * prefetch next tile's (rec, nf, ef) into regs during MFMA+epilogue
//      * W1 B-fragments register-resident (no VMEM in MFMA loop -> no vmcnt waits)
//      * lgkm-only barriers: atomics are never drained inside the loop
//      * nf double-buffer [2][64][128] + ef [64][64], 16B-slot XOR swizzle
//        (slot ^ row&7, both sides); M[32][128] f32 aliases the just-read nf tile
//      LDS 40.5KB -> 3 blocks/CU. ----
__global__ __launch_bounds__(256, 3) void edge_kernel(const short* __restrict__ nf_bf,
                                                      const float* __restrict__ edge_feats,
                                                      const int4* __restrict__ s_edges,
                                                      const short* __restrict__ w1t,
                                                      const float* __restrict__ b1,
                                                      float* __restrict__ hagg) {
  __shared__ __align__(16) short XN[2][64 * 128];   // nf tiles (16KB each)
  __shared__ __align__(16) short XE[64 * 64];       // ef tile (8KB)
  __shared__ int srcs[64];

  const int tid = threadIdx.x;
  const int lane = tid & 63;
  const int wv = tid >> 6;
  const int m16 = lane & 15;
  const int quad = lane >> 4;
  const int r = tid >> 2, q = tid & 3;
  const int rx = r & 7;            // write-side swizzle key
  const int mx = m16 & 7;          // read-side swizzle key

  const int e0 = blockIdx.x * (64 * TPB_E);

  float bias[2];
#pragma unroll
  for (int nt = 0; nt < 2; ++nt) bias[nt] = b1[wv * 32 + nt * 16 + m16];

  // W1 fragments, resident across all tiles
  bf16x8 bfrag[6][2];
#pragma unroll
  for (int ks = 0; ks < 6; ++ks)
#pragma unroll
    for (int nt = 0; nt < 2; ++nt)
      bfrag[ks][nt] = *(const bf16x8*)(w1t + (wv * 32 + nt * 16 + m16) * K1 + ks * 32 + quad * 8);

  // ---- prologue: prefetch tile 0 ----
  int4 rec = s_edges[e0 + r];
  bf16x8 pn[4];
  float4 pe[4];
  {
    const bf16x8* np = (const bf16x8*)(nf_bf + (size_t)rec.y * NDIM) + q * 4;
#pragma unroll
    for (int j = 0; j < 4; ++j) pn[j] = np[j];
    const float4* ep = (const float4*)(edge_feats + (size_t)rec.z * EDIM) + q * 4;
#pragma unroll
    for (int j = 0; j < 4; ++j) pe[j] = ep[j];
  }

  for (int t = 0; t < TPB_E; ++t) {
    short* xn = XN[t & 1];

    // ---- stage tile t from prefetch regs (XOR-swizzled 16B slots) ----
    {
      short* rowp = xn + r * 128;
#pragma unroll
      for (int j = 0; j < 4; ++j)
        *(bf16x8*)(rowp + (((q * 4 + j) ^ rx) << 3)) = pn[j];
      bf16x4 c0 = pack4(pe[0]), c1 = pack4(pe[1]), c2 = pack4(pe[2]), c3 = pack4(pe[3]);
      bf16x8 p0, p1;
      p0[0]=c0[0]; p0[1]=c0[1]; p0[2]=c0[2]; p0[3]=c0[3];
      p0[4]=c1[0]; p0[5]=c1[1]; p0[6]=c1[2]; p0[7]=c1[3];
      p1[0]=c2[0]; p1[1]=c2[1]; p1[2]=c2[2]; p1[3]=c2[3];
      p1[4]=c3[0]; p1[5]=c3[1]; p1[6]=c3[2]; p1[7]=c3[3];
      short* erow = XE + r * 64;
      *(bf16x8*)(erow + (((q * 2 + 0) ^ rx) << 3)) = p0;
      *(bf16x8*)(erow + (((q * 2 + 1) ^ rx) << 3)) = p1;
      if (q == 0) srcs[r] = rec.x;
    }
    __syncthreads();   // the only vmcnt-draining barrier per tile

    // ---- prefetch tile t+1 (lands during MFMA + epilogue) ----
    if (t + 1 < TPB_E) {
      rec = s_edges[e0 + (t + 1) * 64 + r];
      const bf16x8* np = (const bf16x8*)(nf_bf + (size_t)rec.y * NDIM) + q * 4;
#pragma unroll
      for (int j = 0; j < 4; ++j) pn[j] = np[j];
      const float4* ep = (const float4*)(edge_feats + (size_t)rec.z * EDIM) + q * 4;
#pragma unroll
      for (int j = 0; j < 4; ++j) pe[j] = ep[j];
    }

    // ---- MFMA: pure LDS reads + register-resident B ----
    f32x4 acc[4][2];
#pragma unroll
    for (int mt = 0; mt < 4; ++mt)
#pragma unroll
      for (int nt = 0; nt < 2; ++nt) acc[mt][nt] = (f32x4){0.f, 0.f, 0.f, 0.f};
#pragma unroll
    for (int ks = 0; ks < 4; ++ks) {
#pragma unroll
      for (int mt = 0; mt < 4; ++mt) {
        bf16x8 a = *(const bf16x8*)(xn + (mt * 16 + m16) * 128 + (((ks * 4 + quad) ^ mx) << 3));
#pragma unroll
        for (int nt = 0; nt < 2; ++nt)
          acc[mt][nt] = __builtin_amdgcn_mfma_f32_16x16x32_bf16(a, bfrag[ks][nt], acc[mt][nt], 0, 0, 0);
      }
    }
#pragma unroll
    for (int ks = 4; ks < 6; ++ks) {
#pragma unroll
      for (int mt = 0; mt < 4; ++mt) {
        bf16x8 a = *(const bf16x8*)(XE + (mt * 16 + m16) * 64 + ((((ks - 4) * 4 + quad) ^ mx) << 3));
#pragma unroll
        for (int nt = 0; nt < 2; ++nt)
          acc[mt][nt] = __builtin_amdgcn_mfma_f32_16x16x32_bf16(a, bfrag[ks][nt], acc[mt][nt], 0, 0, 0);
      }
    }
    wg_barrier_lds();   // all waves done reading xn/XE; M may alias xn

    // ---- epilogue: two 32-row halves, M[32][128] f32 aliases xn ----
    float* M = (float*)xn;
#pragma unroll
    for (int h = 0; h < 2; ++h) {
#pragma unroll
      for (int nt = 0; nt < 2; ++nt) {
        const int col = wv * 32 + nt * 16 + m16;
        const float bb = bias[nt];
#pragma unroll
        for (int mt2 = 0; mt2 < 2; ++mt2) {
          const int mt = h * 2 + mt2;
#pragma unroll
          for (int i = 0; i < 4; ++i) {
            float v = acc[mt][nt][i] + bb;
            v = v >= 0.f ? v : 0.2f * v;
            M[(mt2 * 16 + quad * 4 + i) * 128 + col] = v;
          }
        }
      }
      wg_barrier_lds();
      {
        const int c = tid & 127;
        const int lr0 = (tid >> 7) * 16;      // 16-row strip
        const int g0 = h * 32 + lr0;
        float a = M[lr0 * 128 + c];
        int prev = srcs[g0];
#pragma unroll 4
        for (int rr = 1; rr < 16; ++rr) {
          int s = srcs[g0 + rr];
          float v = M[(lr0 + rr) * 128 + c];
          if (s != prev) {
            atomicAdd(&hagg[(size_t)prev * NDIM + c], a);
            a = v;
            prev = s;
          } else {
            a += v;
          }
        }
        atomicAdd(&hagg[(size_t)prev * NDIM + c], a);
      }
      wg_barrier_lds();   // strips done: M reusable / srcs rewritable
    }
  }
}

// ---- node kernel: agg = hagg@W2 + deg*b2; out = lrelu(concat(x,agg)@U1+ub1)@U2+ub2
//      32-row tiles: LDS 25.7KB -> 6 blocks/CU ----
__global__ __launch_bounds__(256) void node_kernel(const short* __restrict__ nf_bf,
                                                   const float* __restrict__ hagg,
                                                   const int* __restrict__ degc,
                                                   const short* __restrict__ w2t,
                                                   const float* __restrict__ b2,
                                                   const short* __restrict__ u1t,
                                                   const float* __restrict__ ub1,
                                                   const short* __restrict__ u2t,
                                                   const float* __restrict__ ub2,
                                                   float* __restrict__ out) {
  __shared__ __align__(16) short AGH[32 * KPA];   // phase1: hagg tile; phase3: h2 tile
  __shared__ __align__(16) short XU[32 * KPU];    // concat(x, agg) tile
  __shared__ float degs[32];

  const int tid = threadIdx.x;
  const int n0 = blockIdx.x * 32;

  if (tid < 32) {
    int node = n0 + tid;
    degs[tid] = (node < NNODES) ? (float)degc[node] : 0.f;
  }
  {
    int r = tid >> 3, q = tid & 7;
    int node = n0 + r; if (node >= NNODES) node = NNODES - 1;
    const float4* hp = (const float4*)(hagg + (size_t)node * NDIM) + q * 4;
    const bf16x8* xp = (const bf16x8*)(nf_bf + (size_t)node * NDIM) + q * 2;
    short* ap = AGH + r * KPA + q * 16;
    short* xq = XU + r * KPU + q * 16;
#pragma unroll
    for (int j = 0; j < 4; ++j) *(bf16x4*)(ap + j * 4) = pack4(hp[j]);
#pragma unroll
    for (int j = 0; j < 2; ++j) *(bf16x8*)(xq + j * 8) = xp[j];
  }
  __syncthreads();

  const int lane = tid & 63;
  const int wv = tid >> 6;
  const int m16 = lane & 15;
  const int quad = lane >> 4;

  f32x4 acc[2][2];

  // ---- GEMM-a: agg = AGH @ W2 (K=128) ----
#pragma unroll
  for (int mt = 0; mt < 2; ++mt)
#pragma unroll
    for (int nt = 0; nt < 2; ++nt)
      acc[mt][nt] = (f32x4){0.f, 0.f, 0.f, 0.f};
#pragma unroll
  for (int ks = 0; ks < 4; ++ks) {
    const int k0 = ks * 32 + quad * 8;
    bf16x8 b[2];
#pragma unroll
    for (int nt = 0; nt < 2; ++nt) {
      int n = wv * 32 + nt * 16 + m16;
      b[nt] = *(const bf16x8*)(w2t + n * NDIM + k0);
    }
#pragma unroll
    for (int mt = 0; mt < 2; ++mt) {
      bf16x8 a = *(const bf16x8*)(AGH + (mt * 16 + m16) * KPA + k0);
#pragma unroll
      for (int nt = 0; nt < 2; ++nt)
        acc[mt][nt] = __builtin_amdgcn_mfma_f32_16x16x32_bf16(a, b[nt], acc[mt][nt], 0, 0, 0);
    }
  }
#pragma unroll
  for (int nt = 0; nt < 2; ++nt) {
    int col = wv * 32 + nt * 16 + m16;
    float bb = b2[col];
#pragma unroll
    for (int mt = 0; mt < 2; ++mt) {
#pragma unroll
      for (int i = 0; i < 4; ++i) {
        int row = mt * 16 + quad * 4 + i;
        float v = acc[mt][nt][i] + degs[row] * bb;
        XU[row * KPU + NDIM + col] = f2bf(v);
      }
    }
  }
  __syncthreads();

  // ---- GEMM-b: t = XU @ U1 (K=256), lrelu -> AGH ----
#pragma unroll
  for (int mt = 0; mt < 2; ++mt)
#pragma unroll
    for (int nt = 0; nt < 2; ++nt)
      acc[mt][nt] = (f32x4){0.f, 0.f, 0.f, 0.f};
#pragma unroll
  for (int ks = 0; ks < 8; ++ks) {
    const int k0 = ks * 32 + quad * 8;
    bf16x8 b[2];
#pragma unroll
    for (int nt = 0; nt < 2; ++nt) {
      int n = wv * 32 + nt * 16 + m16;
      b[nt] = *(const bf16x8*)(u1t + n * K2 + k0);
    }
#pragma unroll
    for (int mt = 0; mt < 2; ++mt) {
      bf16x8 a = *(const bf16x8*)(XU + (mt * 16 + m16) * KPU + k0);
#pragma unroll
      for (int nt = 0; nt < 2; ++nt)
        acc[mt][nt] = __builtin_amdgcn_mfma_f32_16x16x32_bf16(a, b[nt], acc[mt][nt], 0, 0, 0);
    }
  }
  __syncthreads();
#pragma unroll
  for (int nt = 0; nt < 2; ++nt) {
    int col = wv * 32 + nt * 16 + m16;
    float bb = ub1[col];
#pragma unroll
    for (int mt = 0; mt < 2; ++mt) {
#pragma unroll
      for (int i = 0; i < 4; ++i) {
        int row = mt * 16 + quad * 4 + i;
        float v = acc[mt][nt][i] + bb;
        v = v >= 0.f ? v : 0.2f * v;
        AGH[row * KPA + col] = f2bf(v);
      }
    }
  }
  __syncthreads();

  // ---- GEMM-c: out = h2 @ U2 (K=128) + ub2 ----
#pragma unroll
  for (int mt = 0; mt < 2; ++mt)
#pragma unroll
    for (int nt = 0; nt < 2; ++nt)
      acc[mt][nt] = (f32x4){0.f, 0.f, 0.f, 0.f};
#pragma unroll
  for (int ks = 0; ks < 4; ++ks) {
    const int k0 = ks * 32 + quad * 8;
    bf16x8 b[2];
#pragma unroll
    for (int nt = 0; nt < 2; ++nt) {
      int n = wv * 32 + nt * 16 + m16;
      b[nt] = *(const bf16x8*)(u2t + n * NDIM + k0);
    }
#pragma unroll
    for (int mt = 0; mt < 2; ++mt) {
      bf16x8 a = *(const bf16x8*)(AGH + (mt * 16 + m16) * KPA + k0);
#pragma unroll
      for (int nt = 0; nt < 2; ++nt)
        acc[mt][nt] = __builtin_amdgcn_mfma_f32_16x16x32_bf16(a, b[nt], acc[mt][nt], 0, 0, 0);
    }
  }
#pragma unroll
  for (int nt = 0; nt < 2; ++nt) {
    int col = wv * 32 + nt * 16 + m16;
    float bb = ub2[col];
#pragma unroll
    for (int mt = 0; mt < 2; ++mt) {
#pragma unroll
      for (int i = 0; i < 4; ++i) {
        int row = mt * 16 + quad * 4 + i;
        int node = n0 + row;
        if (node < NNODES)
          out[(size_t)node * NDIM + col] = acc[mt][nt][i] + bb;
      }
    }
  }
}

extern "C" void kernel_launch(void* const* d_in, const int* in_sizes, int n_in,
                              void* d_out, int out_size, void* d_ws, size_t ws_size,
                              hipStream_t stream) {
  const float* node_feats = (const float*)d_in[0];
  const float* edge_feats = (const float*)d_in[1];
  const float* msg_w1 = (const float*)d_in[2];
  const float* msg_b1 = (const float*)d_in[3];
  const float* msg_w2 = (const float*)d_in[4];
  const float* msg_b2 = (const float*)d_in[5];
  const float* upd_w1 = (const float*)d_in[6];
  const float* upd_b1 = (const float*)d_in[7];
  const float* upd_w2 = (const float*)d_in[8];
  const float* upd_b2 = (const float*)d_in[9];
  const int* eidx = (const int*)d_in[10];

  // ws layout (16B-aligned sections)
  float* hagg   = (float*)d_ws;                        // N*128 f32
  int* cnt      = (int*)(hagg + (size_t)NNODES * NDIM);// N (zeroed with hagg)
  int* row_ptr  = cnt + NNODES;                        // N
  int* bsum     = row_ptr + NNODES;                    // 256
  int* bscan    = bsum + 256;                          // 256
  int4* s_edges = (int4*)(bscan + 256);                // E int4
  short* w1t    = (short*)(s_edges + NEDGES);          // 128*K1 bf16
  short* w2t    = w1t + 128 * K1;
  short* u1t    = w2t + 128 * 128;
  short* u2t    = u1t + 128 * K2;
  short* nf_bf  = u2t + 128 * 128;                     // N*128 bf16

  hipMemsetAsync(d_ws, 0, (size_t)(NNODES * NDIM + NNODES) * sizeof(float), stream);

  cvt_kernel<<<(NNODES * NDIM / 4 + 255) / 256, 256, 0, stream>>>(node_feats, nf_bf,
                                                                  NNODES * NDIM);
  wt_all_kernel<<<(90112 + 255) / 256, 256, 0, stream>>>(msg_w1, msg_w2, upd_w1, upd_w2,
                                                         w1t, w2t, u1t, u2t);

  hist_kernel<<<NEDGES / 256, 256, 0, stream>>>(eidx, cnt);
  scan_reduce_kernel<<<NB, 256, 0, stream>>>(cnt, bsum);
  scan_top_kernel<<<1, 256, 0, stream>>>(bsum, bscan);
  scan_down_kernel<<<NB, 256, 0, stream>>>(cnt, bscan, row_ptr);
  permute_kernel<<<NEDGES / 256, 256, 0, stream>>>(eidx, row_ptr, cnt, s_edges);

  edge_kernel<<<NEDGES / (64 * TPB_E), 256, 0, stream>>>(nf_bf, edge_feats, s_edges,
                                                         w1t, msg_b1, hagg);
  node_kernel<<<(NNODES + 31) / 32, 256, 0, stream>>>(nf_bf, hagg, cnt,
                                                      w2t, msg_b2, u1t, upd_b1,
                                                      u2t, upd_b2, (float*)d_out);
}